// Round 1
// 462.841 us; speedup vs baseline: 1.1813x; 1.1813x over previous
//
#include <hip/hip_runtime.h>
#include <hip/hip_bf16.h>

// BasicCae: x[256,28224] fp32, W_enc[1500,28224], b_enc[1500], W_dec[28224,1500], b_dec[28224]
// out: y_out[256,28224] fp32 ++ jac_reg scalar (at index 7225344)
//
// R6: fused-convert GEMMs. The separate fp32->bf16 weight-convert passes
// (wcvt_enc/wcvt_dec: ~508 MB of traffic + serialization) are folded into
// the GEMMs: B (weights) is reg-staged fp32->pack2->ds_write per K-step,
// A (xbf / yenc, already bf16) stays on the global_load_lds direct path.
// M-tile = 256 (full batch) so each weight element is fetched exactly once.
// rn2 (enc row norms) computed inline during enc B staging (exact fp32).
// B is software-prefetched one K-step ahead so its HBM latency overlaps the
// A async16 latency and drains at the same barrier.

#define BATCH 256
#define IN    28224
#define FEAT  1500
#define FPAD  1536   /* enc N padding & partial stride */
#define KPAD  1504   /* dec K padding (1500 -> 47*32)  */
#define ENC_S 21     /* enc split-K factor; kchunk = 1344 = 42*32 */

typedef __attribute__((ext_vector_type(8))) short short8;   // 8 bf16
typedef __attribute__((ext_vector_type(4))) float f32x4;    // MFMA acc

__device__ __forceinline__ unsigned pack2(float lo, float hi) {
    unsigned a = __float_as_uint(lo) + 0x8000u;
    unsigned b = __float_as_uint(hi) + 0x8000u;
    return __builtin_amdgcn_perm(b, a, 0x07060302);  // (hi16(b)<<16)|hi16(a)
}
__device__ __forceinline__ unsigned short f2bf(float f) {
    unsigned u = __float_as_uint(f);
    return (unsigned short)((u + 0x7FFFu + ((u >> 16) & 1u)) >> 16);
}

// async 16B global -> LDS (direct, no VGPR roundtrip); dest = uniform base + lane*16
__device__ __forceinline__ void async16(const unsigned short* g, unsigned short* l) {
    __builtin_amdgcn_global_load_lds(
        (const __attribute__((address_space(1))) unsigned int*)g,
        (__attribute__((address_space(3))) unsigned int*)l,
        16, 0, 0);
}

// ================= streaming converts =================

__global__ __launch_bounds__(256) void cvt_x(const float* __restrict__ x,
                                             unsigned short* __restrict__ xbf) {
    int idx = blockIdx.x * 256 + threadIdx.x;       // 7056*256 float4s
    float4 v = ((const float4*)x)[idx];
    ((uint2*)xbf)[idx] = make_uint2(pack2(v.x, v.y), pack2(v.z, v.w));
}

// ================= fused-convert GEMMs =================
// Tile 256(M) x 64(N), BK=32, 4 waves; wave tile 64(M) x 64(N), acc[4][4].
// A: bf16 in global, staged via global_load_lds (4 async16 per wave/iter,
//    linear LDS rows of 64B -- required by the uniform-base+lane*16 rule).
// B: fp32 weights, reg-staged: thread t owns row t>>2, two float4 per iter,
//    pack2 -> 2x ds_write_b64. Prefetched one K-step ahead.

// Encoder: part[s] = xbf[256 rows] . We^T[64 rows, fp32] over K-chunk s.
// Also accumulates rn2[f] = ||W_enc[f,:]||^2 (exact fp32) via atomics.
__global__ __launch_bounds__(256) void enc_fused(const unsigned short* __restrict__ xbf,
                                                 const float* __restrict__ We,
                                                 float* __restrict__ part,
                                                 float* __restrict__ rn2) {
    __shared__ unsigned short As[256 * 32];
    __shared__ unsigned short Bs[64 * 32];

    const int n0 = blockIdx.x * 64;                  // feature base (24 tiles -> 1536)
    const int kb = blockIdx.y * 1344;                // split-K chunk (42 iters)
    const int t    = threadIdx.x;
    const int lane = t & 63;
    const int w    = t >> 6;
    const int l15  = lane & 15;
    const int quad = lane >> 4;

    // A staging: wave w owns rows w*64 .. w*64+63
    const unsigned short* ga = xbf + (long)(w * 64 + (lane >> 2)) * IN + kb + (lane & 3) * 8;
    unsigned short* la = As + (w * 64) * 32;

    // B staging: thread t owns weight row br, 8 floats per iter
    const int br = t >> 2;                           // 0..63
    const int bf_ = n0 + br;                         // feature index
    const bool bvalid = bf_ < FEAT;
    const float* bsrc = We + (long)(bvalid ? bf_ : FEAT - 1) * IN + kb + (t & 3) * 8;
    unsigned short* bdst = Bs + br * 32 + (t & 3) * 8;

    float rsq = 0.f;
    f32x4 acc[4][4];
#pragma unroll
    for (int mt = 0; mt < 4; ++mt)
#pragma unroll
        for (int nt = 0; nt < 4; ++nt) { f32x4 z = {0.f,0.f,0.f,0.f}; acc[mt][nt] = z; }

    float4 v0 = *(const float4*)(bsrc);
    float4 v1 = *(const float4*)(bsrc + 4);

    for (int k = 0; k < 1344; k += 32) {
        __syncthreads();                             // prev iter's ds_reads done
        async16(ga + k,            la);
        async16(ga + 16 * IN + k,  la + 16 * 32);
        async16(ga + 32 * IN + k,  la + 32 * 32);
        async16(ga + 48 * IN + k,  la + 48 * 32);
        uint2 p0 = make_uint2(pack2(v0.x, v0.y), pack2(v0.z, v0.w));
        uint2 p1 = make_uint2(pack2(v1.x, v1.y), pack2(v1.z, v1.w));
        if (!bvalid) { p0 = make_uint2(0u, 0u); p1 = make_uint2(0u, 0u); }
        *(uint2*)bdst       = p0;
        *(uint2*)(bdst + 4) = p1;
        rsq += v0.x*v0.x + v0.y*v0.y + v0.z*v0.z + v0.w*v0.w
             + v1.x*v1.x + v1.y*v1.y + v1.z*v1.z + v1.w*v1.w;
        const int kn = k + 32;
        if (kn < 1344) {                             // prefetch next K-step's B
            v0 = *(const float4*)(bsrc + kn);
            v1 = *(const float4*)(bsrc + kn + 4);
        }
        __syncthreads();                             // vmcnt+lgkm drain: LDS ready

        short8 a[4], b[4];
#pragma unroll
        for (int mt = 0; mt < 4; ++mt)
            a[mt] = *(const short8*)(As + (w * 64 + mt * 16 + l15) * 32 + quad * 8);
#pragma unroll
        for (int nt = 0; nt < 4; ++nt)
            b[nt] = *(const short8*)(Bs + (nt * 16 + l15) * 32 + quad * 8);
#pragma unroll
        for (int mt = 0; mt < 4; ++mt)
#pragma unroll
            for (int nt = 0; nt < 4; ++nt)
                acc[mt][nt] = __builtin_amdgcn_mfma_f32_16x16x32_bf16(a[mt], b[nt], acc[mt][nt], 0, 0, 0);
    }

    float* ps = part + (long)blockIdx.y * (BATCH * FPAD);
#pragma unroll
    for (int nt = 0; nt < 4; ++nt) {
        const int col = n0 + nt * 16 + l15;          // < 1536, padded, no guard
#pragma unroll
        for (int mt = 0; mt < 4; ++mt) {
            const int row = w * 64 + mt * 16 + quad * 4;
#pragma unroll
            for (int r = 0; r < 4; ++r)
                ps[(long)(row + r) * FPAD + col] = acc[mt][nt][r];
        }
    }

    // rn2: reduce rsq over the 4 threads sharing a row (lanes differ in bits 0..1)
    rsq += __shfl_xor(rsq, 1);
    rsq += __shfl_xor(rsq, 2);
    if ((lane & 3) == 0 && bvalid) atomicAdd(&rn2[bf_], rsq);
}

// Reduce 21 fp32 partials + bias -> sigmoid -> yenc bf16 [256][1504] + jac.
__global__ __launch_bounds__(256) void act_jac_f(const float* __restrict__ part,
                                                 const float* __restrict__ be,
                                                 const float* __restrict__ rn2,
                                                 unsigned short* __restrict__ yenc,
                                                 float* __restrict__ jac) {
    const int b = blockIdx.y;
    const int f = blockIdx.x * 256 + threadIdx.x;   // 0..1535
    float local = 0.0f;
    unsigned short h = 0;
    if (f < FEAT) {
        float p = be[f];
#pragma unroll 3
        for (int s = 0; s < ENC_S; ++s)
            p += part[(long)(s * BATCH + b) * FPAD + f];
        float y = 1.0f / (1.0f + __expf(-p));
        h = f2bf(y);
        float sg = y * (1.0f - y);
        local = sg * sg * rn2[f];
    }
    if (f < KPAD) yenc[b * KPAD + f] = h;           // zeros for 1500..1503

    float v = local;
#pragma unroll
    for (int off = 32; off > 0; off >>= 1) v += __shfl_down(v, off);
    __shared__ float red[4];
    if ((threadIdx.x & 63) == 0) red[threadIdx.x >> 6] = v;
    __syncthreads();
    if (threadIdx.x == 0) atomicAdd(jac, red[0] + red[1] + red[2] + red[3]);
}

// Decoder: out = sigmoid(yenc[256 rows, bf16] . Wd^T[64 rows, fp32] + b_dec); K = 1504.
__global__ __launch_bounds__(256) void dec_fused(const unsigned short* __restrict__ yenc,
                                                 const float* __restrict__ Wd,
                                                 const float* __restrict__ bd,
                                                 float* __restrict__ out) {
    __shared__ unsigned short As[256 * 32];
    __shared__ unsigned short Bs[64 * 32];

    const int n0 = blockIdx.x * 64;                  // 441 tiles * 64 = 28224 exact
    const int t    = threadIdx.x;
    const int lane = t & 63;
    const int w    = t >> 6;
    const int l15  = lane & 15;
    const int quad = lane >> 4;

    const unsigned short* ga = yenc + (long)(w * 64 + (lane >> 2)) * KPAD + (lane & 3) * 8;
    unsigned short* la = As + (w * 64) * 32;

    const int br = t >> 2;                           // 0..63
    const int bn = n0 + br;                          // output-col index, always < 28224
    const float* bsrc = Wd + (long)bn * FEAT + (t & 3) * 8;
    unsigned short* bdst = Bs + br * 32 + (t & 3) * 8;

    f32x4 acc[4][4];
#pragma unroll
    for (int mt = 0; mt < 4; ++mt)
#pragma unroll
        for (int nt = 0; nt < 4; ++nt) { f32x4 z = {0.f,0.f,0.f,0.f}; acc[mt][nt] = z; }

    float4 v0 = *(const float4*)(bsrc);              // k=0: cols < 32, all valid
    float4 v1 = *(const float4*)(bsrc + 4);

    for (int k = 0; k < KPAD; k += 32) {
        __syncthreads();
        async16(ga + k,              la);
        async16(ga + 16 * KPAD + k,  la + 16 * 32);
        async16(ga + 32 * KPAD + k,  la + 32 * 32);
        async16(ga + 48 * KPAD + k,  la + 48 * 32);
        *(uint2*)bdst       = make_uint2(pack2(v0.x, v0.y), pack2(v0.z, v0.w));
        *(uint2*)(bdst + 4) = make_uint2(pack2(v1.x, v1.y), pack2(v1.z, v1.w));
        const int kn = k + 32;
        if (kn < KPAD) {                             // prefetch next K-step's B
            v0 = *(const float4*)(bsrc + kn);        // v0 cols always < 1500
            const int cc = kn + (t & 3) * 8 + 4;     // first col of v1
            if (cc + 3 < FEAT) v1 = *(const float4*)(bsrc + kn + 4);
            else               v1 = make_float4(0.f, 0.f, 0.f, 0.f);  // pad 1500..1503
        }
        __syncthreads();

        short8 a[4], b[4];
#pragma unroll
        for (int mt = 0; mt < 4; ++mt)
            a[mt] = *(const short8*)(As + (w * 64 + mt * 16 + l15) * 32 + quad * 8);
#pragma unroll
        for (int nt = 0; nt < 4; ++nt)
            b[nt] = *(const short8*)(Bs + (nt * 16 + l15) * 32 + quad * 8);
#pragma unroll
        for (int mt = 0; mt < 4; ++mt)
#pragma unroll
            for (int nt = 0; nt < 4; ++nt)
                acc[mt][nt] = __builtin_amdgcn_mfma_f32_16x16x32_bf16(a[mt], b[nt], acc[mt][nt], 0, 0, 0);
    }

#pragma unroll
    for (int nt = 0; nt < 4; ++nt) {
        const int col = n0 + nt * 16 + l15;
        const float bias = bd[col];
#pragma unroll
        for (int mt = 0; mt < 4; ++mt) {
            const int row = w * 64 + mt * 16 + quad * 4;
#pragma unroll
            for (int r = 0; r < 4; ++r) {
                float v = acc[mt][nt][r] + bias;
                out[(long)(row + r) * IN + col] = 1.0f / (1.0f + __expf(-v));
            }
        }
    }
}

// ================= R4 fallback path (proven; used if ws too small) =================
#define LDA 40

__global__ __launch_bounds__(256) void enc_gemm(const unsigned short* __restrict__ xbf,
                                                const float* __restrict__ We,
                                                float* __restrict__ preact,
                                                float* __restrict__ rn2) {
    __shared__ unsigned short As[256 * LDA];
    __shared__ unsigned short Bs[64 * LDA];
    const int n0 = blockIdx.x * 64;
    const int kb = blockIdx.y * 672;
    const int t = threadIdx.x, lane = t & 63, w = t >> 6, l15 = lane & 15, quad = lane >> 4;
    const unsigned short* asrc = xbf + (long)(t >> 2) * IN + (t & 3) * 8 + kb;
    unsigned short* adst = As + (t >> 2) * LDA + (t & 3) * 8;
    const int brow = t >> 3, bc4 = t & 7;
    const int f0 = n0 + brow, f1 = f0 + 32;
    const float* bsrc0 = We + (long)(f0 < FEAT ? f0 : FEAT - 1) * IN + bc4 * 4 + kb;
    const float* bsrc1 = We + (long)(f1 < FEAT ? f1 : FEAT - 1) * IN + bc4 * 4 + kb;
    unsigned short* bdst0 = Bs + brow * LDA + bc4 * 4;
    unsigned short* bdst1 = bdst0 + 32 * LDA;
    float rsq0 = 0.f, rsq1 = 0.f;
    f32x4 acc[4][4];
#pragma unroll
    for (int mt = 0; mt < 4; ++mt)
#pragma unroll
        for (int nt = 0; nt < 4; ++nt) { f32x4 z = {0.f,0.f,0.f,0.f}; acc[mt][nt] = z; }
    for (int k = 0; k < 672; k += 32) {
        short8 av[4];
#pragma unroll
        for (int j = 0; j < 4; ++j) av[j] = *(const short8*)(asrc + (long)64 * j * IN + k);
        const float4 bv0 = *(const float4*)(bsrc0 + k);
        const float4 bv1 = *(const float4*)(bsrc1 + k);
        __syncthreads();
#pragma unroll
        for (int j = 0; j < 4; ++j) *(short8*)(adst + 64 * j * LDA) = av[j];
        *(uint2*)bdst0 = make_uint2(pack2(bv0.x, bv0.y), pack2(bv0.z, bv0.w));
        *(uint2*)bdst1 = make_uint2(pack2(bv1.x, bv1.y), pack2(bv1.z, bv1.w));
        rsq0 += bv0.x*bv0.x + bv0.y*bv0.y + bv0.z*bv0.z + bv0.w*bv0.w;
        rsq1 += bv1.x*bv1.x + bv1.y*bv1.y + bv1.z*bv1.z + bv1.w*bv1.w;
        __syncthreads();
        short8 a[4], b[4];
#pragma unroll
        for (int mt = 0; mt < 4; ++mt) a[mt] = *(const short8*)(As + (w * 64 + mt * 16 + l15) * LDA + quad * 8);
#pragma unroll
        for (int nt = 0; nt < 4; ++nt) b[nt] = *(const short8*)(Bs + (nt * 16 + l15) * LDA + quad * 8);
#pragma unroll
        for (int mt = 0; mt < 4; ++mt)
#pragma unroll
            for (int nt = 0; nt < 4; ++nt)
                acc[mt][nt] = __builtin_amdgcn_mfma_f32_16x16x32_bf16(a[mt], b[nt], acc[mt][nt], 0, 0, 0);
    }
#pragma unroll
    for (int nt = 0; nt < 4; ++nt) {
        const int col = n0 + nt * 16 + l15;
        if (col < FEAT) {
#pragma unroll
            for (int mt = 0; mt < 4; ++mt) {
                float* p = preact + (long)(w * 64 + mt * 16 + quad * 4) * FEAT + col;
#pragma unroll
                for (int r = 0; r < 4; ++r) atomicAdd(p + (long)r * FEAT, acc[mt][nt][r]);
            }
        }
    }
    {
        float v0 = rsq0, v1 = rsq1;
#pragma unroll
        for (int off = 1; off < 8; off <<= 1) { v0 += __shfl_xor(v0, off); v1 += __shfl_xor(v1, off); }
        if ((lane & 7) == 0) {
            if (f0 < FEAT) atomicAdd(&rn2[f0], v0);
            if (f1 < FEAT) atomicAdd(&rn2[f1], v1);
        }
    }
}

__global__ __launch_bounds__(256) void act_jac(const float* __restrict__ preact,
                                               const float* __restrict__ be,
                                               const float* __restrict__ rn2,
                                               unsigned short* __restrict__ yenc,
                                               float* __restrict__ jac) {
    const int b = blockIdx.y;
    const int f = blockIdx.x * 256 + threadIdx.x;
    float local = 0.0f;
    unsigned short h = 0;
    if (f < FEAT) {
        float p = preact[b * FEAT + f] + be[f];
        float y = 1.0f / (1.0f + __expf(-p));
        h = f2bf(y);
        float s = y * (1.0f - y);
        local = s * s * rn2[f];
    }
    yenc[b * FPAD + f] = h;
    float v = local;
#pragma unroll
    for (int off = 32; off > 0; off >>= 1) v += __shfl_down(v, off);
    __shared__ float red[4];
    if ((threadIdx.x & 63) == 0) red[threadIdx.x >> 6] = v;
    __syncthreads();
    if (threadIdx.x == 0) atomicAdd(jac, red[0] + red[1] + red[2] + red[3]);
}

__global__ __launch_bounds__(256) void dec_gemm(const unsigned short* __restrict__ yenc,
                                                const float* __restrict__ Wd,
                                                const float* __restrict__ bd,
                                                float* __restrict__ out) {
    __shared__ unsigned short As[128 * LDA];
    __shared__ unsigned short Bs[64 * LDA];
    const int m0 = (blockIdx.x & 1) * 128;
    const int n0 = (blockIdx.x >> 1) * 64;
    const int t = threadIdx.x, lane = t & 63, w = t >> 6, l15 = lane & 15, quad = lane >> 4;
    const int mrow = (w >> 1) * 64, ncol = (w & 1) * 32;
    const unsigned short* asrc = yenc + (long)(m0 + (t >> 2)) * FPAD + (t & 3) * 8;
    unsigned short* adst = As + (t >> 2) * LDA + (t & 3) * 8;
    const float* bsrc = Wd + (long)(n0 + (t >> 3)) * FEAT + (t & 7) * 4;
    unsigned short* bdst = Bs + (t >> 3) * LDA + (t & 7) * 4;
    f32x4 acc[4][2];
#pragma unroll
    for (int mt = 0; mt < 4; ++mt)
#pragma unroll
        for (int nt = 0; nt < 2; ++nt) { f32x4 z = {0.f,0.f,0.f,0.f}; acc[mt][nt] = z; }
    for (int k = 0; k < 1504; k += 32) {
        short8 av[2];
#pragma unroll
        for (int j = 0; j < 2; ++j) av[j] = *(const short8*)(asrc + (long)64 * j * FPAD + k);
        float4 bv0, bv1;
        if (k < 1472) {
            bv0 = *(const float4*)(bsrc + k);
            bv1 = *(const float4*)(bsrc + (long)32 * FEAT + k);
        } else {
            if ((t & 7) == 7) { bv0 = make_float4(0,0,0,0); bv1 = bv0; }
            else {
                bv0 = *(const float4*)(bsrc + k);
                bv1 = *(const float4*)(bsrc + (long)32 * FEAT + k);
            }
        }
        __syncthreads();
#pragma unroll
        for (int j = 0; j < 2; ++j) *(short8*)(adst + 64 * j * LDA) = av[j];
        *(uint2*)bdst = make_uint2(pack2(bv0.x, bv0.y), pack2(bv0.z, bv0.w));
        *(uint2*)(bdst + 32 * LDA) = make_uint2(pack2(bv1.x, bv1.y), pack2(bv1.z, bv1.w));
        __syncthreads();
        short8 a[4], b[2];
#pragma unroll
        for (int mt = 0; mt < 4; ++mt) a[mt] = *(const short8*)(As + (mrow + mt * 16 + l15) * LDA + quad * 8);
#pragma unroll
        for (int nt = 0; nt < 2; ++nt) b[nt] = *(const short8*)(Bs + (ncol + nt * 16 + l15) * LDA + quad * 8);
#pragma unroll
        for (int mt = 0; mt < 4; ++mt)
#pragma unroll
            for (int nt = 0; nt < 2; ++nt)
                acc[mt][nt] = __builtin_amdgcn_mfma_f32_16x16x32_bf16(a[mt], b[nt], acc[mt][nt], 0, 0, 0);
    }
#pragma unroll
    for (int nt = 0; nt < 2; ++nt) {
        const int col = n0 + ncol + nt * 16 + l15;
        const float bias = bd[col];
#pragma unroll
        for (int mt = 0; mt < 4; ++mt) {
            const int row = m0 + mrow + mt * 16 + quad * 4;
#pragma unroll
            for (int r = 0; r < 4; ++r) {
                float v = acc[mt][nt][r] + bias;
                out[(long)(row + r) * IN + col] = 1.0f / (1.0f + __expf(-v));
            }
        }
    }
}

// ================= launch =================
extern "C" void kernel_launch(void* const* d_in, const int* in_sizes, int n_in,
                              void* d_out, int out_size, void* d_ws, size_t ws_size,
                              hipStream_t stream) {
    const float* x  = (const float*)d_in[0];
    const float* We = (const float*)d_in[1];
    const float* be = (const float*)d_in[2];
    const float* Wd = (const float*)d_in[3];
    const float* bd = (const float*)d_in[4];
    float* out = (float*)d_out;
    char* ws = (char*)d_ws;

    // Fast-path ws layout (16B-aligned), total 48,257,024 B:
    //   xbf   bf16 [256][28224]    @ 0           (14,450,688)
    //   yenc  bf16 [256][1504]     @ 14,450,688  (   770,048)
    //   part  fp32 [21][256][1536] @ 15,220,736  (33,030,144)
    //   rn2   fp32 [1536]          @ 48,250,880  (     6,144)
    if (ws_size >= 48257024ull) {
        unsigned short* xbf  = (unsigned short*)ws;
        unsigned short* yenc = (unsigned short*)(ws + 14450688);
        float* part          = (float*)(ws + 15220736);
        float* rn2           = (float*)(ws + 48250880);

        hipMemsetAsync(rn2, 0, 6144, stream);
        hipMemsetAsync(out + 7225344, 0, 4, stream);        // jac slot

        cvt_x<<<7056, 256, 0, stream>>>(x, xbf);
        enc_fused<<<dim3(24, ENC_S), 256, 0, stream>>>(xbf, We, part, rn2);
        act_jac_f<<<dim3(6, 256), 256, 0, stream>>>(part, be, rn2, yenc, out + 7225344);
        dec_fused<<<441, 256, 0, stream>>>(yenc, Wd, bd, out);
    } else {
        // R4 fallback: preact fp32 @0 (1,536,000) | rn2 @1,536,000 | yenc @1,542,144 | xbf @2,328,576
        float* preact        = (float*)ws;
        float* rn2           = (float*)(ws + 1536000);
        unsigned short* yenc = (unsigned short*)(ws + 1542144);
        unsigned short* xbf  = (unsigned short*)(ws + 2328576);

        hipMemsetAsync(ws, 0, 1542144, stream);
        hipMemsetAsync(out + 7225344, 0, 4, stream);

        cvt_x<<<7056, 256, 0, stream>>>(x, xbf);
        enc_gemm<<<dim3(24, 42), 256, 0, stream>>>(xbf, We, preact, rn2);
        act_jac<<<dim3(6, 256), 256, 0, stream>>>(preact, be, rn2, yenc, out + 7225344);
        dec_gemm<<<882, 256, 0, stream>>>(yenc, Wd, bd, out);
    }
}